// Round 5
// baseline (337.868 us; speedup 1.0000x reference)
//
#include <hip/hip_runtime.h>
#include <math.h>

#define T_TOTAL 16384
#define HDIM    2048
#define NEXP    64

// ---------------------------------------------------------------------------
// Hybrid scalar/LDS GEMM:  partial[t][ks][e] = sum_k x[t][k] * w[e][k]
//
// Block: 256 threads = 4 waves, covers 256 tokens x 64 experts.
//   wave  -> 16 experts (wave-uniform => W via s_load, SGPR operand in FMA)
//   lane  -> 4 consecutive tokens (lane-linear ds_read_b128 from LDS)
// Per-lane tile 4 tokens x 16 experts = 64 acc VGPRs.
// LDS holds only X ([k][token], stride 260: ==4 mod 32 -> 2-way staging
// writes (free), ==0 mod 4 -> 16B-aligned b128 reads, lane-linear ->
// conflict-free). LDS traffic: 0.25 B/FMA -> 32 B/cyc/CU at full VALU,
// far under the ~85 B/cyc LDS ceiling (R4 was LDS-BW-bound at 1.0 B/FMA).
// ---------------------------------------------------------------------------
template<int KS>
__global__ __launch_bounds__(256, 4)
void router_gemm_kernel(const float* __restrict__ x,
                        const float* __restrict__ w,
                        float* __restrict__ partial)
{
    constexpr int KSLICE = HDIM / KS;   // 128 for KS=16
    constexpr int BK     = 16;
    constexpr int XS_ST  = 260;

    __shared__ __align__(16) float Xs[BK][XS_ST];

    const int tid  = threadIdx.x;
    const int lane = tid & 63;
    const int wv   = __builtin_amdgcn_readfirstlane(tid >> 6);  // wave id (uniform)
    const int tb   = blockIdx.x & 63;    // token block (64 x 256 tokens)
    const int ks   = blockIdx.x >> 6;    // k-slice
    const int t0   = tb * 256;
    const int k0   = ks * KSLICE;

    const int e0   = wv * 16;            // this wave's 16 experts (uniform)
    const int kq   = tid & 3;            // staging k-quad
    const int rr   = tid >> 2;           // staging row 0..63
    const int l4   = lane * 4;           // this lane's 4 tokens (within block)

    const float* wb = w + (size_t)e0 * HDIM + k0;   // uniform pointer -> s_load

    float acc[4][16];
#pragma unroll
    for (int t = 0; t < 4; ++t)
#pragma unroll
        for (int j = 0; j < 16; ++j) acc[t][j] = 0.0f;

#pragma unroll 1
    for (int kc = 0; kc < KSLICE; kc += BK) {
        __syncthreads();

        // stage X tile: 256 tokens x 16 k, transposed -> [k][token]
        {
            const float* xg = x + (size_t)t0 * HDIM + (k0 + kc) + kq * 4;
#pragma unroll
            for (int p = 0; p < 4; ++p) {
                const int r = p * 64 + rr;
                const float4 v = *(const float4*)(xg + (size_t)r * HDIM);
                Xs[kq * 4 + 0][r] = v.x;
                Xs[kq * 4 + 1][r] = v.y;
                Xs[kq * 4 + 2][r] = v.z;
                Xs[kq * 4 + 3][r] = v.w;
            }
        }
        __syncthreads();

#pragma unroll
        for (int kk = 0; kk < BK; kk += 4) {
            // 4 k-steps of this lane's 4 tokens (lane-linear b128 reads)
            float4 xr[4];
#pragma unroll
            for (int c = 0; c < 4; ++c)
                xr[c] = *(const float4*)&Xs[kk + c][l4];

            // 16 experts x 4 k x 4 tokens; W values come from s_load
#pragma unroll
            for (int j = 0; j < 16; ++j) {
                const float* wr = wb + (size_t)j * HDIM + (kc + kk);
                const float w0 = wr[0], w1 = wr[1], w2 = wr[2], w3 = wr[3];
                acc[0][j] = fmaf(xr[0].x, w0, acc[0][j]);
                acc[1][j] = fmaf(xr[0].y, w0, acc[1][j]);
                acc[2][j] = fmaf(xr[0].z, w0, acc[2][j]);
                acc[3][j] = fmaf(xr[0].w, w0, acc[3][j]);
                acc[0][j] = fmaf(xr[1].x, w1, acc[0][j]);
                acc[1][j] = fmaf(xr[1].y, w1, acc[1][j]);
                acc[2][j] = fmaf(xr[1].z, w1, acc[2][j]);
                acc[3][j] = fmaf(xr[1].w, w1, acc[3][j]);
                acc[0][j] = fmaf(xr[2].x, w2, acc[0][j]);
                acc[1][j] = fmaf(xr[2].y, w2, acc[1][j]);
                acc[2][j] = fmaf(xr[2].z, w2, acc[2][j]);
                acc[3][j] = fmaf(xr[2].w, w2, acc[3][j]);
                acc[0][j] = fmaf(xr[3].x, w3, acc[0][j]);
                acc[1][j] = fmaf(xr[3].y, w3, acc[1][j]);
                acc[2][j] = fmaf(xr[3].z, w3, acc[2][j]);
                acc[3][j] = fmaf(xr[3].w, w3, acc[3][j]);
            }
        }
    }

    // write partial [t][ks][e0..e0+15]
    float* pp = partial + ((size_t)(t0 + l4) * KS + ks) * NEXP + e0;
#pragma unroll
    for (int t = 0; t < 4; ++t) {
        float* q = pp + (size_t)t * KS * NEXP;
        *(float4*)(q +  0) = make_float4(acc[t][ 0], acc[t][ 1], acc[t][ 2], acc[t][ 3]);
        *(float4*)(q +  4) = make_float4(acc[t][ 4], acc[t][ 5], acc[t][ 6], acc[t][ 7]);
        *(float4*)(q +  8) = make_float4(acc[t][ 8], acc[t][ 9], acc[t][10], acc[t][11]);
        *(float4*)(q + 12) = make_float4(acc[t][12], acc[t][13], acc[t][14], acc[t][15]);
    }
}

// ---------------------------------------------------------------------------
// Sum KS partials + sigmoid + biased top-8 (desc, ties -> lower idx) +
// renorm * 2.5. One wave per token, lane = expert.
// ---------------------------------------------------------------------------
__global__ __launch_bounds__(256)
void router_topk_kernel(const float* __restrict__ partial,
                        const float* __restrict__ bias,
                        float* __restrict__ out_scores,
                        float* __restrict__ out_idx,
                        int ksCount)
{
    const int token = blockIdx.x * 4 + (threadIdx.x >> 6);
    const int lane  = threadIdx.x & 63;

    const float* pt = partial + (size_t)token * ksCount * NEXP + lane;
    float logit = 0.0f;
    for (int s = 0; s < ksCount; ++s) logit += pt[(size_t)s * NEXP];

    const float score = 1.0f / (1.0f + expf(-logit));
    float key = score + bias[lane];

    float myscore = 0.0f;
    int   myidx   = 0;
    float denom   = 0.0f;

#pragma unroll
    for (int r = 0; r < 8; ++r) {
        float bk = key;
        int   bi = lane;
#pragma unroll
        for (int off = 32; off > 0; off >>= 1) {
            const float ok = __shfl_xor(bk, off);
            const int   oi = __shfl_xor(bi, off);
            if (ok > bk || (ok == bk && oi < bi)) { bk = ok; bi = oi; }
        }
        const float wsc = __shfl(score, bi);   // raw (unbiased) winner score
        denom += wsc;
        if (lane == r)  { myscore = wsc; myidx = bi; }
        if (lane == bi) key = -__builtin_inff();
    }

    const float factor = 2.5f / (denom + 1e-20f);
    if (lane < 8) {
        out_scores[(size_t)token * 8 + lane] = myscore * factor;
        out_idx  [(size_t)token * 8 + lane] = (float)myidx;
    }
}

// ---------------------------------------------------------------------------
extern "C" void kernel_launch(void* const* d_in, const int* in_sizes, int n_in,
                              void* d_out, int out_size, void* d_ws, size_t ws_size,
                              hipStream_t stream)
{
    const float* x    = (const float*)d_in[0];   // [4,4096,2048] f32
    const float* bias = (const float*)d_in[1];   // [64] f32
    const float* w    = (const float*)d_in[2];   // [64,2048] f32

    float* out     = (float*)d_out;
    float* partial = (float*)d_ws;

    const size_t bytesPerSlice = (size_t)T_TOTAL * NEXP * 4;   // 4 MiB

    int ksCount;
    if (ws_size >= 16 * bytesPerSlice) {         // 64 MiB (confirmed available)
        ksCount = 16;
        router_gemm_kernel<16><<<dim3(64 * 16), dim3(256), 0, stream>>>(x, w, partial);
    } else if (ws_size >= 8 * bytesPerSlice) {
        ksCount = 8;
        router_gemm_kernel<8><<<dim3(64 * 8), dim3(256), 0, stream>>>(x, w, partial);
    } else {
        ksCount = 4;
        router_gemm_kernel<4><<<dim3(64 * 4), dim3(256), 0, stream>>>(x, w, partial);
    }

    router_topk_kernel<<<dim3(T_TOTAL / 4), dim3(256), 0, stream>>>(
        partial, bias, out, out + (size_t)T_TOTAL * 8, ksCount);
}